// Round 9
// baseline (125.534 us; speedup 1.0000x reference)
//
#include <hip/hip_runtime.h>
#include <hip/hip_bf16.h>

#define BATCH 8
#define CH    64
#define NPIX  65536
#define NHEAD 2
#define HDIM  32
#define P1_BLOCKS 128  // pass-1 blocks per batch; 2 supertiles of 256px each

typedef __attribute__((ext_vector_type(8))) short bf16x8;
typedef __attribute__((ext_vector_type(4))) short bf16x4;
typedef __attribute__((ext_vector_type(4))) float f32x4;

#define MFMA32(a, b, c) __builtin_amdgcn_mfma_f32_16x16x32_bf16(a, b, c, 0, 0, 0)

#if __has_builtin(__builtin_amdgcn_mfma_f32_16x16x16_bf16)
typedef __attribute__((ext_vector_type(4))) __bf16 bf16v4;
#define MFMA16(a, b, c) __builtin_amdgcn_mfma_f32_16x16x16_bf16( \
    __builtin_bit_cast(bf16v4, (a)), __builtin_bit_cast(bf16v4, (b)), (c), 0, 0, 0)
#else
#define MFMA16(a, b, c) __builtin_amdgcn_mfma_f32_16x16x16bf16_1k((a), (b), (c), 0, 0, 0)
#endif

// pack two f32 -> one u32 holding two bf16 (RNE)
__device__ __forceinline__ unsigned rne_pk(float lo, float hi) {
    unsigned ua = __float_as_uint(lo); ua += 0x7fffu + ((ua >> 16) & 1u);
    unsigned ub = __float_as_uint(hi); ub += 0x7fffu + ((ub >> 16) & 1u);
    return (ua >> 16) | (ub & 0xffff0000u);
}

__device__ __forceinline__ bf16x8 pack8(const float* f) {
    int4 iv;
    iv.x = (int)rne_pk(f[0], f[1]);
    iv.y = (int)rne_pk(f[2], f[3]);
    iv.z = (int)rne_pk(f[4], f[5]);
    iv.w = (int)rne_pk(f[6], f[7]);
    return *reinterpret_cast<bf16x8*>(&iv);
}

__device__ __forceinline__ float phi_f(float t) {
    return t > 0.0f ? t + 1.0f : __expf(t);
}

// A-layout fragment of row-major W[*][64]: lane gets (m = r0+l%16, k = k0+(l/16)*8+e)
// (identical lane data also serves as the B-frag of W^T)
__device__ __forceinline__ bf16x8 load_w_frag(const float* W, int r0, int k0, int lane) {
    const float* p = W + (size_t)(r0 + (lane & 15)) * 64 + k0 + ((lane >> 4) << 3);
    float f[8];
    #pragma unroll
    for (int e = 0; e < 8; e++) f[e] = p[e];
    return pack8(f);
}

// ---------------- Pass 1 (fused): dense x read -> LDS transpose -> GEMM1 -> GEMM2(16x16x16)
//                  + bf16 x^T side-product for pass 2. grid (P1_BLOCKS, 8), block 256.
__global__ __launch_bounds__(256) void la_pass1(
    const float* __restrict__ x, const float* __restrict__ qkv_w,
    float* __restrict__ partials, unsigned short* __restrict__ xt)
{
    __shared__ __align__(16) unsigned char smem[33024];   // xls[64][258] bf16; rbuf overlays
    unsigned short* xls = (unsigned short*)smem;

    const int tid  = threadIdx.x;
    const int lane = tid & 63;
    const int wv   = __builtin_amdgcn_readfirstlane(tid >> 6);
    const int b    = blockIdx.y;
    const int g    = lane >> 4;
    const int li   = lane & 15;

    // preload W^T B-frags for k|v output channels (qkv_w rows 64..191)
    bf16x8 Wf[8][2];
    #pragma unroll
    for (int j = 0; j < 8; j++)
        #pragma unroll
        for (int ks = 0; ks < 2; ks++)
            Wf[j][ks] = load_w_frag(qkv_w, 64 + 16 * j, 32 * ks, lane);

    f32x4 kvacc[2][2][2];  // [head][c-tile][d-tile], 16x16x16 accum
    #pragma unroll
    for (int h = 0; h < 2; h++)
        #pragma unroll
        for (int m2 = 0; m2 < 2; m2++)
            #pragma unroll
            for (int nt = 0; nt < 2; nt++)
                kvacc[h][m2][nt] = (f32x4){0.f, 0.f, 0.f, 0.f};

    const float* xb = x + (size_t)b * CH * NPIX;
    unsigned short* xtb = xt + (size_t)b * NPIX * CH;

    for (int it = 0; it < 2; it++) {
        const int px0 = (blockIdx.x * 2 + it) * 256;

        // ---- phase A: dense stage. Each wave-instr = 1KB contiguous (one channel row).
        #pragma unroll
        for (int k4 = 0; k4 < 4; k4++) {
            float4 f[4];
            #pragma unroll
            for (int k = 0; k < 4; k++)
                f[k] = *reinterpret_cast<const float4*>(
                    xb + (size_t)(wv + 4 * (4 * k4 + k)) * NPIX + px0 + 4 * lane);
            #pragma unroll
            for (int k = 0; k < 4; k++)
                *reinterpret_cast<uint2*>(&xls[(wv + 4 * (4 * k4 + k)) * 258 + 4 * lane]) =
                    make_uint2(rne_pk(f[k].x, f[k].y), rne_pk(f[k].z, f[k].w));
        }
        __syncthreads();

        // ---- phase B: each wave MFMAs its 64-px quarter (4 subtiles of 16 px)
        #pragma unroll
        for (int mt = 0; mt < 4; mt++) {
            const int pxl = 64 * wv + 16 * mt + li;

            // A-frags of X^T: (m = px = li, k = ch = 32ks+8g+e). Bank-conflict-free column read.
            bf16x8 xa[2];
            #pragma unroll
            for (int ks = 0; ks < 2; ks++) {
                unsigned v[8];
                #pragma unroll
                for (int e = 0; e < 8; e++)
                    v[e] = xls[(32 * ks + 8 * g + e) * 258 + pxl];
                int4 iv;
                iv.x = (int)(v[0] | (v[1] << 16));
                iv.y = (int)(v[2] | (v[3] << 16));
                iv.z = (int)(v[4] | (v[5] << 16));
                iv.w = (int)(v[6] | (v[7] << 16));
                xa[ks] = *reinterpret_cast<bf16x8*>(&iv);
            }

            // GEMM1: C1_j = X^T * W^T (m=px, n=c16j); phi on k; pack C rows -> 16x16x16 frags.
            // C layout (col=l&15=c, row=4g+r=px) == A/B frag layout of 16x16x16 (k=4g+e=px).
            bf16x4 kA[4], vB[4];
            #pragma unroll
            for (int j = 0; j < 8; j++) {
                f32x4 acc = (f32x4){0.f, 0.f, 0.f, 0.f};
                acc = MFMA32(xa[0], Wf[j][0], acc);
                acc = MFMA32(xa[1], Wf[j][1], acc);
                float v0 = acc[0], v1 = acc[1], v2 = acc[2], v3 = acc[3];
                if (j < 4) { v0 = phi_f(v0); v1 = phi_f(v1); v2 = phi_f(v2); v3 = phi_f(v3); }
                uint2 p = make_uint2(rne_pk(v0, v1), rne_pk(v2, v3));
                bf16x4 r = __builtin_bit_cast(bf16x4, p);
                if (j < 4) kA[j] = r; else vB[j - 4] = r;
            }

            // GEMM2: KV += phi_k * v^T over this 16-px subtile (K=16)
            #pragma unroll
            for (int h = 0; h < 2; h++)
                #pragma unroll
                for (int m2 = 0; m2 < 2; m2++)
                    #pragma unroll
                    for (int nt = 0; nt < 2; nt++)
                        kvacc[h][m2][nt] = MFMA16(kA[2 * h + m2], vB[2 * h + nt], kvacc[h][m2][nt]);
        }

        // ---- xt side-product: column-read xls, write dense bf16 [px][64ch] rows
        #pragma unroll
        for (int seg = 0; seg < 4; seg++) {
            const int pxl = 64 * seg + (tid >> 2);
            const int c0  = (tid & 3) * 16;
            unsigned d[8];
            #pragma unroll
            for (int i = 0; i < 8; i++) {
                unsigned lo = xls[(c0 + 2 * i) * 258 + pxl];
                unsigned hi = xls[(c0 + 2 * i + 1) * 258 + pxl];
                d[i] = lo | (hi << 16);
            }
            unsigned short* dst = xtb + (size_t)(px0 + pxl) * CH + c0;
            int4 lo4; lo4.x = (int)d[0]; lo4.y = (int)d[1]; lo4.z = (int)d[2]; lo4.w = (int)d[3];
            int4 hi4; hi4.x = (int)d[4]; hi4.y = (int)d[5]; hi4.z = (int)d[6]; hi4.w = (int)d[7];
            *reinterpret_cast<int4*>(dst)     = lo4;
            *reinterpret_cast<int4*>(dst + 8) = hi4;
        }
        __syncthreads();   // xls reuse / rbuf overlay protection
    }

    // ---- block reduce (4 waves), store partial slice
    float* rbuf = (float*)smem;  // [4][2048] f32 = 32KB <= 33KB
    #pragma unroll
    for (int h = 0; h < 2; h++)
        #pragma unroll
        for (int m2 = 0; m2 < 2; m2++)
            #pragma unroll
            for (int nt = 0; nt < 2; nt++) {
                const int t = (h * 2 + m2) * 2 + nt;
                #pragma unroll
                for (int r = 0; r < 4; r++)
                    rbuf[wv * 2048 + t * 256 + (4 * g + r) * 16 + li] = kvacc[h][m2][nt][r];
            }
    __syncthreads();

    float* outp = partials + ((size_t)b * P1_BLOCKS + blockIdx.x) * 2048;
    #pragma unroll
    for (int i = 0; i < 8; i++) {
        const int idx = i * 256 + tid;
        const float sum = rbuf[idx] + rbuf[2048 + idx] + rbuf[4096 + idx] + rbuf[6144 + idx];
        const int t = idx >> 8, within = idx & 255;
        const int row = within >> 4, col = within & 15;
        const int h = t >> 2, m2 = (t >> 1) & 1, nt = t & 1;
        outp[(h * 32 + 16 * m2 + row) * 32 + 16 * nt + col] = sum;
    }
}

// ---------------- Reduce: kv[b][e] = sum_j partials[b][j][e] ----------------
__global__ __launch_bounds__(256) void la_reduce(
    const float* __restrict__ partials, float* __restrict__ kv)
{
    const int b = blockIdx.x >> 3;
    const int e = (blockIdx.x & 7) * 256 + threadIdx.x;
    const float* p = partials + (size_t)b * P1_BLOCKS * 2048 + e;
    float s0 = 0.f, s1 = 0.f, s2 = 0.f, s3 = 0.f;
    #pragma unroll 8
    for (int j = 0; j < P1_BLOCKS; j += 4) {
        s0 += p[(size_t)j * 2048];
        s1 += p[(size_t)(j + 1) * 2048];
        s2 += p[(size_t)(j + 2) * 2048];
        s3 += p[(size_t)(j + 3) * 2048];
    }
    kv[(size_t)b * 2048 + e] = (s0 + s1) + (s2 + s3);
}

// ---------------- Pass 2: y = proj * (KV^T * phi(q)), x from bf16 xt, NT y stores ----------------
// grid (256, 8), block 256, zero barriers.
__global__ __launch_bounds__(256) void la_pass2(
    const unsigned short* __restrict__ xt, const float* __restrict__ qkv_w,
    const float* __restrict__ proj_w, const float* __restrict__ kv,
    float* __restrict__ y)
{
    __shared__ __align__(16) unsigned short sm2[4][2][16][72];  // [wave][q|out][px][ch+pad]

    const int tid  = threadIdx.x;
    const int lane = tid & 63;
    const int wv   = __builtin_amdgcn_readfirstlane(tid >> 6);
    const int b    = blockIdx.y;
    const int g    = lane >> 4;
    const int li   = lane & 15;

    unsigned short* qT = &sm2[wv][0][0][0];
    unsigned short* oT = &sm2[wv][1][0][0];

    bf16x8 Aq[4][2], Ap[4][2], Akv[2][2];
    #pragma unroll
    for (int mt = 0; mt < 4; mt++)
        #pragma unroll
        for (int ks = 0; ks < 2; ks++) {
            Aq[mt][ks] = load_w_frag(qkv_w, 16 * mt, 32 * ks, lane);
            Ap[mt][ks] = load_w_frag(proj_w, 16 * mt, 32 * ks, lane);
        }
    const float* kvb = kv + (size_t)b * NHEAD * HDIM * HDIM;
    #pragma unroll
    for (int h = 0; h < 2; h++)
        #pragma unroll
        for (int mtd = 0; mtd < 2; mtd++) {
            float f[8];
            #pragma unroll
            for (int e = 0; e < 8; e++)
                f[e] = kvb[h * 1024 + (8 * g + e) * 32 + 16 * mtd + li];  // KV^T[d][c]=KV[c][d]
            Akv[h][mtd] = pack8(f);
        }

    const unsigned short* xtb = xt + (size_t)b * NPIX * CH;
    float*                yb  = y  + (size_t)b * CH * NPIX;

    for (int s = blockIdx.x * 4 + wv; s < 4096; s += 1024) {
        const int px0 = s * 16;

        // B-frags of x from xt: dense b128 loads
        bf16x8 bx[2];
        const unsigned short* xp = xtb + (size_t)(px0 + li) * CH + 8 * g;
        bx[0] = *reinterpret_cast<const bf16x8*>(xp);
        bx[1] = *reinterpret_cast<const bf16x8*>(xp + 32);

        // q = Wq * X, phi, packed store to qT[px][c]
        #pragma unroll
        for (int mt = 0; mt < 4; mt++) {
            f32x4 acc = (f32x4){0.f, 0.f, 0.f, 0.f};
            acc = MFMA32(Aq[mt][0], bx[0], acc);
            acc = MFMA32(Aq[mt][1], bx[1], acc);
            const float p0 = phi_f(acc[0]), p1 = phi_f(acc[1]);
            const float p2 = phi_f(acc[2]), p3 = phi_f(acc[3]);
            *reinterpret_cast<uint2*>(qT + li * 72 + 16 * mt + 4 * g) =
                make_uint2(rne_pk(p0, p1), rne_pk(p2, p3));
        }

        // out = KV^T * q_phi per head
        #pragma unroll
        for (int h = 0; h < 2; h++) {
            const bf16x8 bq = *reinterpret_cast<const bf16x8*>(qT + li * 72 + 32 * h + 8 * g);
            #pragma unroll
            for (int mtd = 0; mtd < 2; mtd++) {
                f32x4 acc = (f32x4){0.f, 0.f, 0.f, 0.f};
                acc = MFMA32(Akv[h][mtd], bq, acc);
                *reinterpret_cast<uint2*>(oT + li * 72 + 32 * h + 16 * mtd + 4 * g) =
                    make_uint2(rne_pk(acc[0], acc[1]), rne_pk(acc[2], acc[3]));
            }
        }

        // y = proj * out, nontemporal stores
        const bf16x8 bo0 = *reinterpret_cast<const bf16x8*>(oT + li * 72 + 8 * g);
        const bf16x8 bo1 = *reinterpret_cast<const bf16x8*>(oT + li * 72 + 32 + 8 * g);
        #pragma unroll
        for (int mt = 0; mt < 4; mt++) {
            f32x4 acc = (f32x4){0.f, 0.f, 0.f, 0.f};
            acc = MFMA32(Ap[mt][0], bo0, acc);
            acc = MFMA32(Ap[mt][1], bo1, acc);
            #pragma unroll
            for (int r = 0; r < 4; r++)
                __builtin_nontemporal_store(acc[r],
                    &yb[(size_t)(16 * mt + 4 * g + r) * NPIX + px0 + li]);
        }
    }
}

extern "C" void kernel_launch(void* const* d_in, const int* in_sizes, int n_in,
                              void* d_out, int out_size, void* d_ws, size_t ws_size,
                              hipStream_t stream) {
    (void)in_sizes; (void)n_in; (void)out_size; (void)ws_size;
    const float* x      = (const float*)d_in[0];
    const float* qkv_w  = (const float*)d_in[1];
    const float* proj_w = (const float*)d_in[2];
    float* yout = (float*)d_out;

    // ws: xt bf16 [8][65536][64] (64MB), partials [8][128][2048] f32 (8MB), kv (64KB)
    unsigned short* xtw      = (unsigned short*)d_ws;
    float*          partials = (float*)(xtw + (size_t)BATCH * NPIX * CH);
    float*          kv       = partials + (size_t)BATCH * P1_BLOCKS * 2048;

    la_pass1 <<<dim3(P1_BLOCKS, BATCH), dim3(256), 0, stream>>>(x, qkv_w, partials, xtw);
    la_reduce<<<dim3(64),               dim3(256), 0, stream>>>(partials, kv);
    la_pass2 <<<dim3(256, BATCH),       dim3(256), 0, stream>>>(xtw, qkv_w, proj_w, kv, yout);
}